// Round 1
// baseline (440.204 us; speedup 1.0000x reference)
//
#include <hip/hip_runtime.h>
#include <hip/hip_bf16.h>
#include <math.h>

#define NB 4
#define NH 16
#define NQ 2048
#define DH 64
#define QBLK 64
#define KVBLK 64
#define NWAVE 4

typedef __attribute__((ext_vector_type(8))) short bf16x8;
typedef __attribute__((ext_vector_type(4))) short bf16x4;
typedef __attribute__((ext_vector_type(4))) float f32x4;

__device__ __forceinline__ short f2bf(float f) {
  unsigned u = __float_as_uint(f);
  u = (u + 0x7FFFu + ((u >> 16) & 1u)) >> 16;
  return (short)(unsigned short)u;
}

__global__ __launch_bounds__(256, 2) void fattn_kernel(
    const float* __restrict__ Q, const float* __restrict__ K,
    const float* __restrict__ V, float* __restrict__ O) {
  // K tile: [KVBLK][DH] bf16, XOR-swizzled (half-index ^= (row&7)<<3)
  __shared__ short k_lds[KVBLK * DH];
  // V tile transposed: [DH][KVBLK] bf16, swizzled
  __shared__ short vt_lds[DH * KVBLK];
  // per-wave P tile: [16][KVBLK] bf16, swizzled
  __shared__ short p_lds[NWAVE][16 * KVBLK];

  const int tid = threadIdx.x;
  const int wid = tid >> 6;
  const int lane = tid & 63;
  const int l16 = lane & 15;
  const int lhi = lane >> 4;

  const int head = blockIdx.y;                  // b*H + h
  const int qrow0 = blockIdx.x * QBLK + wid * 16;
  const size_t base = (size_t)head * NQ * DH;

  // ---- hoist Q fragments to registers (scale 1/sqrt(D)=0.125 folded in) ----
  // A-frag layout (16x16x32): lane holds A[q=l16][d = dstep*32 + lhi*8 + i]
  bf16x8 qf[2];
  {
    const float* qp = Q + base + (size_t)(qrow0 + l16) * DH + lhi * 8;
#pragma unroll
    for (int dstep = 0; dstep < 2; ++dstep) {
      const float4 a = *(const float4*)(qp + dstep * 32);
      const float4 b = *(const float4*)(qp + dstep * 32 + 4);
      bf16x8 t;
      t[0] = f2bf(a.x * 0.125f); t[1] = f2bf(a.y * 0.125f);
      t[2] = f2bf(a.z * 0.125f); t[3] = f2bf(a.w * 0.125f);
      t[4] = f2bf(b.x * 0.125f); t[5] = f2bf(b.y * 0.125f);
      t[6] = f2bf(b.z * 0.125f); t[7] = f2bf(b.w * 0.125f);
      qf[dstep] = t;
    }
  }

  f32x4 o_acc[4];
  float m_run[4], l_run[4];
#pragma unroll
  for (int dt = 0; dt < 4; ++dt) o_acc[dt] = f32x4{0.f, 0.f, 0.f, 0.f};
#pragma unroll
  for (int r = 0; r < 4; ++r) { m_run[r] = -INFINITY; l_run[r] = 0.f; }

  for (int it = 0; it < NQ / KVBLK; ++it) {
    const int kv0 = it * KVBLK;
    __syncthreads();  // previous iteration's LDS reads done before overwrite

    // ---- stage K (row-major) and V (transposed) tiles, fp32 -> bf16 ----
#pragma unroll
    for (int j = 0; j < 4; ++j) {
      const int flat4 = tid + j * 256;      // float4 index in 64x64 tile
      const int row = flat4 >> 4;           // key row 0..63
      const int c4 = flat4 & 15;            // float4 column
      const float4 kd = *(const float4*)(K + base + (size_t)(kv0 + row) * DH + c4 * 4);
      bf16x4 kb;
      kb[0] = f2bf(kd.x); kb[1] = f2bf(kd.y); kb[2] = f2bf(kd.z); kb[3] = f2bf(kd.w);
      const int kidx = ((row << 6) + c4 * 4) ^ ((row & 7) << 3);
      *(bf16x4*)(&k_lds[kidx]) = kb;

      const float4 vd = *(const float4*)(V + base + (size_t)(kv0 + row) * DH + c4 * 4);
      const short vb0 = f2bf(vd.x), vb1 = f2bf(vd.y), vb2 = f2bf(vd.z), vb3 = f2bf(vd.w);
      const int d0 = c4 * 4;
      vt_lds[(((d0 + 0) << 6) + row) ^ (((d0 + 0) & 7) << 3)] = vb0;
      vt_lds[(((d0 + 1) << 6) + row) ^ (((d0 + 1) & 7) << 3)] = vb1;
      vt_lds[(((d0 + 2) << 6) + row) ^ (((d0 + 2) & 7) << 3)] = vb2;
      vt_lds[(((d0 + 3) << 6) + row) ^ (((d0 + 3) & 7) << 3)] = vb3;
    }
    __syncthreads();

    // ---- S = Q K^T for this wave's 16 rows x 64 keys ----
    f32x4 s[4];
#pragma unroll
    for (int c = 0; c < 4; ++c) {
      s[c] = f32x4{0.f, 0.f, 0.f, 0.f};
#pragma unroll
      for (int dstep = 0; dstep < 2; ++dstep) {
        const int krow = c * 16 + l16;  // B-frag: lane holds K[key=l16(+16c)][d]
        const int kidx = ((krow << 6) + dstep * 32 + lhi * 8) ^ ((krow & 7) << 3);
        const bf16x8 kf = *(const bf16x8*)(&k_lds[kidx]);
        s[c] = __builtin_amdgcn_mfma_f32_16x16x32_bf16(qf[dstep], kf, s[c], 0, 0, 0);
      }
    }

    // ---- online softmax; C layout: row = lhi*4 + r, col(key) = c*16 + l16 ----
    float p[4][4];
#pragma unroll
    for (int r = 0; r < 4; ++r) {
      float mx = fmaxf(fmaxf(s[0][r], s[1][r]), fmaxf(s[2][r], s[3][r]));
      mx = fmaxf(mx, __shfl_xor(mx, 1));
      mx = fmaxf(mx, __shfl_xor(mx, 2));
      mx = fmaxf(mx, __shfl_xor(mx, 4));
      mx = fmaxf(mx, __shfl_xor(mx, 8));
      const float m_new = fmaxf(m_run[r], mx);
      const float alpha = __expf(m_run[r] - m_new);
      m_run[r] = m_new;
      float rs = 0.f;
#pragma unroll
      for (int c = 0; c < 4; ++c) {
        p[c][r] = __expf(s[c][r] - m_new);
        rs += p[c][r];
      }
      rs += __shfl_xor(rs, 1);
      rs += __shfl_xor(rs, 2);
      rs += __shfl_xor(rs, 4);
      rs += __shfl_xor(rs, 8);
      l_run[r] = l_run[r] * alpha + rs;
#pragma unroll
      for (int dt = 0; dt < 4; ++dt) o_acc[dt][r] *= alpha;
    }

    // ---- P -> LDS (per-wave region, bf16, swizzled) ----
    short* pl = p_lds[wid];
#pragma unroll
    for (int r = 0; r < 4; ++r) {
      const int qrow = lhi * 4 + r;
#pragma unroll
      for (int c = 0; c < 4; ++c) {
        pl[((qrow << 6) + c * 16 + l16) ^ ((qrow & 7) << 3)] = f2bf(p[c][r]);
      }
    }

    // ---- O += P V ----
#pragma unroll
    for (int t = 0; t < 2; ++t) {
      // A-frag: lane holds P[q=l16][k = t*32 + lhi*8 + i]
      const int pidx = ((l16 << 6) + t * 32 + lhi * 8) ^ ((l16 & 7) << 3);
      const bf16x8 pa = *(const bf16x8*)(&pl[pidx]);
#pragma unroll
      for (int dt = 0; dt < 4; ++dt) {
        // B-frag: lane holds V[k = t*32 + lhi*8 + i][d = dt*16 + l16]
        const int d = dt * 16 + l16;
        const int vidx = ((d << 6) + t * 32 + lhi * 8) ^ ((d & 7) << 3);
        const bf16x8 vf = *(const bf16x8*)(&vt_lds[vidx]);
        o_acc[dt] = __builtin_amdgcn_mfma_f32_16x16x32_bf16(pa, vf, o_acc[dt], 0, 0, 0);
      }
    }
  }

  // ---- epilogue: divide by l, store fp32 ----
#pragma unroll
  for (int r = 0; r < 4; ++r) {
    const float inv = 1.f / l_run[r];
    const int qrow = qrow0 + lhi * 4 + r;
    float* op = O + base + (size_t)qrow * DH + l16;
#pragma unroll
    for (int dt = 0; dt < 4; ++dt) op[dt * 16] = o_acc[dt][r] * inv;
  }
}

extern "C" void kernel_launch(void* const* d_in, const int* in_sizes, int n_in,
                              void* d_out, int out_size, void* d_ws, size_t ws_size,
                              hipStream_t stream) {
  const float* q = (const float*)d_in[0];
  const float* k = (const float*)d_in[1];
  const float* v = (const float*)d_in[2];
  float* o = (float*)d_out;
  dim3 grid(NQ / QBLK, NB * NH, 1);
  fattn_kernel<<<grid, dim3(256, 1, 1), 0, stream>>>(q, k, v, o);
}

// Round 2
// 205.769 us; speedup vs baseline: 2.1393x; 2.1393x over previous
//
#include <hip/hip_runtime.h>
#include <hip/hip_bf16.h>
#include <math.h>

#define NBATCH 4
#define NHEAD 16
#define NSEQ 2048
#define DHEAD 64
#define QBLK 128   // 4 waves x 32 q rows
#define KVBLK 64
#define NTILE (NSEQ / KVBLK)

typedef __attribute__((ext_vector_type(8))) short bf16x8;
typedef __attribute__((ext_vector_type(4))) short short4v;
typedef __attribute__((ext_vector_type(16))) float f32x16;

__device__ __forceinline__ unsigned short f2bf(float f) {
  unsigned u = __float_as_uint(f);
  u = (u + 0x7FFFu + ((u >> 16) & 1u)) >> 16;
  return (unsigned short)u;
}
__device__ __forceinline__ unsigned pack2(float a, float b) {
  return (unsigned)f2bf(a) | ((unsigned)f2bf(b) << 16);
}

// S^T = mfma(A=K, B=Q): C[key][q], q = lane&31 -> softmax lane-local.
// O^T = mfma(A=V^T, B=P^T): C[d][q], q = lane&31 -> rescale lane-local.
// K LDS: frag-major. slot(sub,kk,hi_d,ch,m2x) holds K[sub*32+kk][ch*16+hi_d*8+(0..7)]
//   byte = sub*4096 + (kk&3)*1024 + hi_d*512 + ch*128 + m2x*16, m2x=(kk>>2)^((kk&3)<<1)
// V LDS: slot(ch,dblk,d5,khi) holds V[ch*16+khi*8+(0..7)][d5+32*dblk]
//   byte = (ch*2+dblk)*1024 + (d5&3)*256 + khi*128 + (d5>>2)*16
__global__ __launch_bounds__(256, 3) void fattn_kernel(
    const float* __restrict__ Q, const float* __restrict__ K,
    const float* __restrict__ V, float* __restrict__ O) {
  __shared__ short klds[4096];  // 8 KB
  __shared__ short vlds[4096];  // 8 KB

  const int tid = threadIdx.x;
  const int l = tid & 63;
  const int wv = tid >> 6;
  const int l31 = l & 31;
  const int HL = l >> 5;
  const bool hib = (HL != 0);

  const int head = blockIdx.y;
  const size_t base = (size_t)head * NSEQ * DHEAD;
  const int q0 = blockIdx.x * QBLK + wv * 32;

  // ---- Q fragments (B-operand): qf[ch] = Q[q=l31][ch*16 + HL*8 + i] * 0.125 ----
  bf16x8 qf[4];
  {
    const float* qrow = Q + base + (size_t)(q0 + l31) * DHEAD + HL * 8;
#pragma unroll
    for (int ch = 0; ch < 4; ++ch) {
      const float4 f0 = *(const float4*)(qrow + ch * 16);
      const float4 f1 = *(const float4*)(qrow + ch * 16 + 4);
      bf16x8 t;
      t[0] = (short)f2bf(f0.x * 0.125f); t[1] = (short)f2bf(f0.y * 0.125f);
      t[2] = (short)f2bf(f0.z * 0.125f); t[3] = (short)f2bf(f0.w * 0.125f);
      t[4] = (short)f2bf(f1.x * 0.125f); t[5] = (short)f2bf(f1.y * 0.125f);
      t[6] = (short)f2bf(f1.z * 0.125f); t[7] = (short)f2bf(f1.w * 0.125f);
      qf[ch] = t;
    }
  }

  // staging thread->element map (wave-coalesced: wave covers 16 rows x 64B)
  const int skey_l = l & 15;                       // + 16*p
  const int sd0 = wv * 16 + ((l >> 4) & 3) * 4;    // d0 of the float4

  // LDS lane read bases (bytes)
  const int kk = l31;
  const int m2x = (kk >> 2) ^ ((kk & 3) << 1);
  const int kread = ((kk & 3) << 10) + (HL << 9) + (m2x << 4);
  const int vread = ((l & 3) << 8) + (HL << 7) + ((l31 >> 2) << 4);

  char* kb = (char*)klds;
  char* vb = (char*)vlds;

  f32x16 o0, o1;
#pragma unroll
  for (int r = 0; r < 16; ++r) { o0[r] = 0.f; o1[r] = 0.f; }
  float m_run = -1e30f, l_run = 0.f;

  for (int it = 0; it < NTILE; ++it) {
    const int kv0 = it * KVBLK;
    __syncthreads();  // previous tile's LDS reads complete

    // ---- stage K and V (fp32 global -> bf16 frag-major LDS) ----
#pragma unroll
    for (int p = 0; p < 4; ++p) {
      const int key = skey_l + 16 * p;
      const float4 kf = *(const float4*)(K + base + (size_t)(kv0 + key) * DHEAD + sd0);
      const float4 vf = *(const float4*)(V + base + (size_t)(kv0 + key) * DHEAD + sd0);
      // K: one ds_write_b64 (4 consecutive d in one slot)
      const int kkw = key & 31;
      const int m2w = (kkw >> 2) ^ ((kkw & 3) << 1);
      const int koff = ((key >> 5) << 12) + ((kkw & 3) << 10) + (((sd0 >> 3) & 1) << 9)
                     + ((sd0 >> 4) << 7) + (m2w << 4) + ((sd0 & 7) << 1);
      short4v kb4;
      kb4[0] = (short)f2bf(kf.x); kb4[1] = (short)f2bf(kf.y);
      kb4[2] = (short)f2bf(kf.z); kb4[3] = (short)f2bf(kf.w);
      *(short4v*)(kb + koff) = kb4;
      // V: 4 scalar b16 writes (transpose scatter), ~2-way by construction
      const int vbase2 = ((p * 2 + (sd0 >> 5)) << 10) + (((key >> 3) & 1) << 7)
                       + (((sd0 & 31) >> 2) << 4) + ((key & 7) << 1);
      *(short*)(vb + vbase2 + 0)   = (short)f2bf(vf.x);
      *(short*)(vb + vbase2 + 256) = (short)f2bf(vf.y);
      *(short*)(vb + vbase2 + 512) = (short)f2bf(vf.z);
      *(short*)(vb + vbase2 + 768) = (short)f2bf(vf.w);
    }
    __syncthreads();

    // ---- S^T = K Q^T : 8 mfma, conflict-free ds_read_b128 ----
    f32x16 s0, s1;
#pragma unroll
    for (int r = 0; r < 16; ++r) { s0[r] = 0.f; s1[r] = 0.f; }
#pragma unroll
    for (int ch = 0; ch < 4; ++ch) {
      const bf16x8 ka0 = *(const bf16x8*)(kb + kread + ch * 128);
      const bf16x8 ka1 = *(const bf16x8*)(kb + kread + ch * 128 + 4096);
      s0 = __builtin_amdgcn_mfma_f32_32x32x16_bf16(ka0, qf[ch], s0, 0, 0, 0);
      s1 = __builtin_amdgcn_mfma_f32_32x32x16_bf16(ka1, qf[ch], s1, 0, 0, 0);
    }

    // ---- online softmax: lane-local over 32 vals + 1 swap with partner ----
    float mx = s0[0];
#pragma unroll
    for (int r = 1; r < 16; ++r) mx = fmaxf(mx, s0[r]);
#pragma unroll
    for (int r = 0; r < 16; ++r) mx = fmaxf(mx, s1[r]);
    mx = fmaxf(mx, __shfl_xor(mx, 32));
    const float m_new = fmaxf(m_run, mx);
    const float alpha = __expf(m_run - m_new);
    m_run = m_new;
    float rsum = 0.f;
#pragma unroll
    for (int r = 0; r < 16; ++r) { s0[r] = __expf(s0[r] - m_new); rsum += s0[r]; }
#pragma unroll
    for (int r = 0; r < 16; ++r) { s1[r] = __expf(s1[r] - m_new); rsum += s1[r]; }
    rsum += __shfl_xor(rsum, 32);
    l_run = l_run * alpha + rsum;
    o0 *= alpha;
    o1 *= alpha;

    // ---- pack P to bf16 pairs, exchange halves ----
    unsigned wreg[2][8], xreg[2][8];
#pragma unroll
    for (int g = 0; g < 8; ++g) {
      wreg[0][g] = pack2(s0[2 * g], s0[2 * g + 1]);
      wreg[1][g] = pack2(s1[2 * g], s1[2 * g + 1]);
    }
#pragma unroll
    for (int sub = 0; sub < 2; ++sub)
#pragma unroll
      for (int g = 0; g < 8; ++g)
        xreg[sub][g] = (unsigned)__shfl_xor((int)wreg[sub][g], 32);

    // ---- O^T += V^T P^T : assemble P B-frags (crow algebra), 8 mfma ----
#pragma unroll
    for (int ch = 0; ch < 4; ++ch) {
      const int sub = ch >> 1, e = ch & 1;
      const unsigned lo0 = hib ? xreg[sub][4 * e + 2] : wreg[sub][4 * e + 0];
      const unsigned lo1 = hib ? xreg[sub][4 * e + 3] : wreg[sub][4 * e + 1];
      const unsigned hi0 = hib ? wreg[sub][4 * e + 2] : xreg[sub][4 * e + 0];
      const unsigned hi1 = hib ? wreg[sub][4 * e + 3] : xreg[sub][4 * e + 1];
      union { unsigned u[4]; bf16x8 h; } pb;
      pb.u[0] = lo0; pb.u[1] = lo1; pb.u[2] = hi0; pb.u[3] = hi1;
      const bf16x8 va0 = *(const bf16x8*)(vb + vread + (ch * 2 + 0) * 1024);
      const bf16x8 va1 = *(const bf16x8*)(vb + vread + (ch * 2 + 1) * 1024);
      o0 = __builtin_amdgcn_mfma_f32_32x32x16_bf16(va0, pb.h, o0, 0, 0, 0);
      o1 = __builtin_amdgcn_mfma_f32_32x32x16_bf16(va1, pb.h, o1, 0, 0, 0);
    }
  }

  // ---- epilogue: lane-local 1/l, d = crow(r,HL)+32*dblk -> float4 stores ----
  const float inv = 1.f / l_run;
  float* orow = O + base + (size_t)(q0 + l31) * DHEAD;
#pragma unroll
  for (int a = 0; a < 4; ++a) {
    float4 v0, v1;
    v0.x = o0[4 * a + 0] * inv; v0.y = o0[4 * a + 1] * inv;
    v0.z = o0[4 * a + 2] * inv; v0.w = o0[4 * a + 3] * inv;
    *(float4*)(orow + 8 * a + 4 * HL) = v0;
    v1.x = o1[4 * a + 0] * inv; v1.y = o1[4 * a + 1] * inv;
    v1.z = o1[4 * a + 2] * inv; v1.w = o1[4 * a + 3] * inv;
    *(float4*)(orow + 8 * a + 4 * HL + 32) = v1;
  }
}

extern "C" void kernel_launch(void* const* d_in, const int* in_sizes, int n_in,
                              void* d_out, int out_size, void* d_ws, size_t ws_size,
                              hipStream_t stream) {
  const float* q = (const float*)d_in[0];
  const float* k = (const float*)d_in[1];
  const float* v = (const float*)d_in[2];
  float* o = (float*)d_out;
  dim3 grid(NSEQ / QBLK, NBATCH * NHEAD, 1);
  fattn_kernel<<<grid, dim3(256, 1, 1), 0, stream>>>(q, k, v, o);
}

// Round 4
// 134.279 us; speedup vs baseline: 3.2783x; 1.5324x over previous
//
#include <hip/hip_runtime.h>
#include <hip/hip_bf16.h>
#include <math.h>

#define NBATCH 4
#define NHEAD 16
#define NSEQ 2048
#define DHEAD 64
#define QBLK 128   // 4 waves x 32 q rows
#define KVBLK 64
#define NTILE (NSEQ / KVBLK)
#define NHTOT (NBATCH * NHEAD)
#define KV_TILE_BYTES 16384
#define QB_BYTES ((size_t)NHTOT * NSEQ * DHEAD * 2)               // 16 MB
#define KVB_BYTES ((size_t)NHTOT * NTILE * (size_t)KV_TILE_BYTES) // 32 MB
#define WS_NEED (QB_BYTES + KVB_BYTES)

typedef __attribute__((ext_vector_type(8))) short bf16x8;
typedef __attribute__((ext_vector_type(4))) short short4v;
typedef __attribute__((ext_vector_type(16))) float f32x16;

union BF8U { unsigned u[4]; bf16x8 v; };

__device__ __forceinline__ unsigned short f2bf(float f) {
  unsigned u = __float_as_uint(f);
  u = (u + 0x7FFFu + ((u >> 16) & 1u)) >> 16;
  return (unsigned short)u;
}
__device__ __forceinline__ unsigned pack2(float a, float b) {
  return (unsigned)f2bf(a) | ((unsigned)f2bf(b) << 16);
}
// v_cvt_pk_bf16_f32: packs two f32 -> one dword of 2x bf16 (RNE). No builtin
// on gfx950 (T12 recipe) -> inline asm.
__device__ __forceinline__ unsigned cvtpk(float a, float b) {
  unsigned r;
  asm("v_cvt_pk_bf16_f32 %0, %1, %2" : "=v"(r) : "v"(a), "v"(b));
  return r;
}
__device__ __forceinline__ void gload_lds16(const void* g, void* l) {
  __builtin_amdgcn_global_load_lds(
      (const __attribute__((address_space(1))) void*)g,
      (__attribute__((address_space(3))) void*)l, 16, 0, 0);
}

// ============ prepass: fp32 -> bf16, K/V re-laid into LDS tile images ==========
// K image byte (8KB/tile): ((key>>5)<<12)|((key&3)<<10)|(hi_d<<9)|(ch<<7)|(m2x<<4)
//   holds K[key][ch*16+hi_d*8 + 0..7], m2x=((key&31)>>2)^((key&3)<<1)
// V image byte (+8192):    (c2<<10)|((d5&3)<<8)|(khi<<7)|((d5>>2)<<4)|((key&7)<<1)
//   holds V[ch*16+khi*8 + 0..7][dblk*32+d5], c2 = ch*2+dblk
__global__ __launch_bounds__(256) void prep_kernel(
    const float* __restrict__ Q, const float* __restrict__ K,
    const float* __restrict__ V, short* __restrict__ Qb, char* __restrict__ KVb) {
  __shared__ float vsm[64][68];
  const int t = threadIdx.x;
  const int bid = blockIdx.x;
  if (bid < 4096) {  // Q convert, scale 1/8 folded
    const size_t e0 = ((size_t)bid * 256 + t) * 8;
    const float4 f0 = *(const float4*)(Q + e0);
    const float4 f1 = *(const float4*)(Q + e0 + 4);
    BF8U u;
    u.u[0] = cvtpk(f0.x * 0.125f, f0.y * 0.125f);
    u.u[1] = cvtpk(f0.z * 0.125f, f0.w * 0.125f);
    u.u[2] = cvtpk(f1.x * 0.125f, f1.y * 0.125f);
    u.u[3] = cvtpk(f1.z * 0.125f, f1.w * 0.125f);
    *(bf16x8*)(Qb + e0) = u.v;
    return;
  }
  const int hb = bid - 4096;       // head*NTILE + tile
  const int head = hb >> 5;
  const int tile = hb & 31;
  const float* kp = K + ((size_t)head * NSEQ + tile * KVBLK) * DHEAD;
  const float* vp = V + ((size_t)head * NSEQ + tile * KVBLK) * DHEAD;
  char* out = KVb + (size_t)hb * KV_TILE_BYTES;
  // ---- K slots (coalesced reads, scattered 16B writes merged in L2) ----
#pragma unroll
  for (int j = 0; j < 2; ++j) {
    const int n = t + j * 256;
    const int key = n >> 3, ch = (n >> 1) & 3, hi = n & 1;
    const int d0 = ch * 16 + hi * 8;
    const float4 f0 = *(const float4*)(kp + key * DHEAD + d0);
    const float4 f1 = *(const float4*)(kp + key * DHEAD + d0 + 4);
    BF8U u;
    u.u[0] = cvtpk(f0.x, f0.y); u.u[1] = cvtpk(f0.z, f0.w);
    u.u[2] = cvtpk(f1.x, f1.y); u.u[3] = cvtpk(f1.z, f1.w);
    const int kk = key & 31;
    const int m2 = (kk >> 2) ^ ((kk & 3) << 1);
    const int off = ((key >> 5) << 12) | ((kk & 3) << 10) | (hi << 9) | (ch << 7) | (m2 << 4);
    *(bf16x8*)(out + off) = u.v;
  }
  // ---- V: coalesced read -> LDS -> transposed slots, coalesced 16B writes ----
#pragma unroll
  for (int p = 0; p < 4; ++p) {
    const int key = (t & 15) + 16 * p;
    const int d0 = (t >> 4) * 4;
    *(float4*)(&vsm[key][d0]) = *(const float4*)(vp + key * DHEAD + d0);
  }
  __syncthreads();
#pragma unroll
  for (int j = 0; j < 2; ++j) {
    const int s = t + j * 256;                 // slot id == (vbyte>>4)
    const int d5 = ((s >> 4) & 3) | ((s & 7) << 2);
    const int khi = (s >> 3) & 1;
    const int c2 = (s >> 6) & 7;
    const int ch = c2 >> 1, dblk = c2 & 1;
    const int d = dblk * 32 + d5;
    const int k0 = ch * 16 + khi * 8;
    BF8U u;
    u.u[0] = cvtpk(vsm[k0 + 0][d], vsm[k0 + 1][d]);
    u.u[1] = cvtpk(vsm[k0 + 2][d], vsm[k0 + 3][d]);
    u.u[2] = cvtpk(vsm[k0 + 4][d], vsm[k0 + 5][d]);
    u.u[3] = cvtpk(vsm[k0 + 6][d], vsm[k0 + 7][d]);
    *(bf16x8*)(out + 8192 + (s << 4)) = u.v;
  }
}

// ===================== main: bf16 flash attention, 2-phase =====================
__global__ __launch_bounds__(256, 4) void fattn_kernel(
    const short* __restrict__ Qb, const char* __restrict__ KVb,
    float* __restrict__ O) {
  __shared__ __align__(128) char smem[2][16384];  // [buf][K 8KB | V 8KB]

  const int tid = threadIdx.x;
  const int l = tid & 63;
  const int wv = tid >> 6;
  const int l31 = l & 31;
  const int HL = l >> 5;
  const bool hib = (HL != 0);

  const int head = blockIdx.x;          // XCD = head%8 -> per-head L2 residency
  const int q0 = blockIdx.y * QBLK + wv * 32;
  const size_t base = (size_t)head * NSEQ * DHEAD;

  // Q fragments (bf16, pre-scaled)
  bf16x8 qf[4];
#pragma unroll
  for (int ch = 0; ch < 4; ++ch)
    qf[ch] = *(const bf16x8*)(Qb + base + (size_t)(q0 + l31) * DHEAD + ch * 16 + HL * 8);

  const int kk = l31;
  const int m2x = (kk >> 2) ^ ((kk & 3) << 1);
  const int kread = ((kk & 3) << 10) + (HL << 9) + (m2x << 4);
  const int vread = 8192 + ((l & 3) << 8) + (HL << 7) + ((l31 >> 2) << 4);

  const char* tb = KVb + (size_t)head * NTILE * KV_TILE_BYTES;

  f32x16 o0, o1;
#pragma unroll
  for (int r = 0; r < 16; ++r) { o0[r] = 0.f; o1[r] = 0.f; }
  float m_run = -1e30f, l_run = 0.f;

  // prologue: stage tile 0 into buf 0 (DMA, linear)
#pragma unroll
  for (int j = 0; j < 4; ++j) {
    const int off = ((wv << 2) + j) << 10;
    gload_lds16(tb + off + l * 16, &smem[0][off]);
  }
  __syncthreads();

  for (int it = 0; it < NTILE; ++it) {
    const char* cb = smem[it & 1];
    // stage next tile into the other buffer (overlaps with compute below)
    if (it + 1 < NTILE) {
      const char* src = tb + (size_t)(it + 1) * KV_TILE_BYTES;
      char* dst = smem[(it + 1) & 1];
#pragma unroll
      for (int j = 0; j < 4; ++j) {
        const int off = ((wv << 2) + j) << 10;
        gload_lds16(src + off + l * 16, dst + off);
      }
    }

    // ---- S^T = K Q^T : 8 mfma, conflict-free ds_read_b128 ----
    f32x16 s0, s1;
#pragma unroll
    for (int r = 0; r < 16; ++r) { s0[r] = 0.f; s1[r] = 0.f; }
#pragma unroll
    for (int ch = 0; ch < 4; ++ch) {
      const bf16x8 ka0 = *(const bf16x8*)(cb + kread + ch * 128);
      const bf16x8 ka1 = *(const bf16x8*)(cb + kread + ch * 128 + 4096);
      s0 = __builtin_amdgcn_mfma_f32_32x32x16_bf16(ka0, qf[ch], s0, 0, 0, 0);
      s1 = __builtin_amdgcn_mfma_f32_32x32x16_bf16(ka1, qf[ch], s1, 0, 0, 0);
    }

    // ---- online softmax (lane-local row, tree reduce, defer-max) ----
    float a[8];
#pragma unroll
    for (int i = 0; i < 8; ++i) a[i] = fmaxf(fmaxf(s0[i], s0[i + 8]), fmaxf(s1[i], s1[i + 8]));
#pragma unroll
    for (int i = 0; i < 4; ++i) a[i] = fmaxf(a[i], a[i + 4]);
    float mx = fmaxf(fmaxf(a[0], a[1]), fmaxf(a[2], a[3]));
    mx = fmaxf(mx, __shfl_xor(mx, 32));
    if (!__all(mx <= m_run + 8.f)) {   // T13: rescale only on real max growth
      const float m_new = fmaxf(m_run, mx);
      const float alpha = __expf(m_run - m_new);
      l_run *= alpha;
      o0 *= alpha;
      o1 *= alpha;
      m_run = m_new;
    }
    float e0[16], e1[16];
#pragma unroll
    for (int r = 0; r < 16; ++r) { e0[r] = __expf(s0[r] - m_run); e1[r] = __expf(s1[r] - m_run); }
    float b[8];
#pragma unroll
    for (int i = 0; i < 8; ++i) b[i] = (e0[i] + e0[i + 8]) + (e1[i] + e1[i + 8]);
#pragma unroll
    for (int i = 0; i < 4; ++i) b[i] += b[i + 4];
    float rsum = (b[0] + b[1]) + (b[2] + b[3]);
    rsum += __shfl_xor(rsum, 32);
    l_run += rsum;

    // ---- pack P to bf16 pairs; exchange only the 8 words the partner needs ----
    unsigned wreg[2][8];
#pragma unroll
    for (int g = 0; g < 8; ++g) {
      wreg[0][g] = cvtpk(e0[2 * g], e0[2 * g + 1]);
      wreg[1][g] = cvtpk(e1[2 * g], e1[2 * g + 1]);
    }
    const int send0[4] = {2, 3, 6, 7};  // what HL=0 sends (HL=1 needs these)
    const int send1[4] = {0, 1, 4, 5};  // what HL=1 sends
    unsigned rx[2][4];
#pragma unroll
    for (int sub = 0; sub < 2; ++sub)
#pragma unroll
      for (int j = 0; j < 4; ++j) {
        const unsigned snd = hib ? wreg[sub][send1[j]] : wreg[sub][send0[j]];
        rx[sub][j] = (unsigned)__shfl_xor((int)snd, 32);
      }

    // ---- O^T += V^T P^T ----
#pragma unroll
    for (int ch = 0; ch < 4; ++ch) {
      const int sub = ch >> 1, e = ch & 1;
      const unsigned own0 = wreg[sub][4 * e + (hib ? 2 : 0)];
      const unsigned own1 = wreg[sub][4 * e + 1 + (hib ? 2 : 0)];
      const unsigned oth0 = rx[sub][2 * e];
      const unsigned oth1 = rx[sub][2 * e + 1];
      BF8U pb;
      pb.u[0] = hib ? oth0 : own0;
      pb.u[1] = hib ? oth1 : own1;
      pb.u[2] = hib ? own0 : oth0;
      pb.u[3] = hib ? own1 : oth1;
      const bf16x8 va0 = *(const bf16x8*)(cb + vread + (ch * 2 + 0) * 1024);
      const bf16x8 va1 = *(const bf16x8*)(cb + vread + (ch * 2 + 1) * 1024);
      o0 = __builtin_amdgcn_mfma_f32_32x32x16_bf16(va0, pb.v, o0, 0, 0, 0);
      o1 = __builtin_amdgcn_mfma_f32_32x32x16_bf16(va1, pb.v, o1, 0, 0, 0);
    }
    __syncthreads();  // next tile staged + everyone done reading cur
  }

  // ---- epilogue ----
  const float inv = 1.f / l_run;
  float* orow = O + base + (size_t)(q0 + l31) * DHEAD;
#pragma unroll
  for (int a2 = 0; a2 < 4; ++a2) {
    float4 v0, v1;
    v0.x = o0[4 * a2 + 0] * inv; v0.y = o0[4 * a2 + 1] * inv;
    v0.z = o0[4 * a2 + 2] * inv; v0.w = o0[4 * a2 + 3] * inv;
    *(float4*)(orow + 8 * a2 + 4 * HL) = v0;
    v1.x = o1[4 * a2 + 0] * inv; v1.y = o1[4 * a2 + 1] * inv;
    v1.z = o1[4 * a2 + 2] * inv; v1.w = o1[4 * a2 + 3] * inv;
    *(float4*)(orow + 8 * a2 + 4 * HL + 32) = v1;
  }
}

// ===================== fallback (proven round-2 kernel) =====================
__global__ __launch_bounds__(256, 3) void fattn_fb(
    const float* __restrict__ Q, const float* __restrict__ K,
    const float* __restrict__ V, float* __restrict__ O) {
  __shared__ short klds[4096];
  __shared__ short vlds[4096];
  const int tid = threadIdx.x;
  const int l = tid & 63;
  const int wv = tid >> 6;
  const int l31 = l & 31;
  const int HL = l >> 5;
  const bool hib = (HL != 0);
  const int head = blockIdx.y;
  const size_t base = (size_t)head * NSEQ * DHEAD;
  const int q0 = blockIdx.x * QBLK + wv * 32;
  bf16x8 qf[4];
  {
    const float* qrow = Q + base + (size_t)(q0 + l31) * DHEAD + HL * 8;
#pragma unroll
    for (int ch = 0; ch < 4; ++ch) {
      const float4 f0 = *(const float4*)(qrow + ch * 16);
      const float4 f1 = *(const float4*)(qrow + ch * 16 + 4);
      bf16x8 t;
      t[0] = (short)f2bf(f0.x * 0.125f); t[1] = (short)f2bf(f0.y * 0.125f);
      t[2] = (short)f2bf(f0.z * 0.125f); t[3] = (short)f2bf(f0.w * 0.125f);
      t[4] = (short)f2bf(f1.x * 0.125f); t[5] = (short)f2bf(f1.y * 0.125f);
      t[6] = (short)f2bf(f1.z * 0.125f); t[7] = (short)f2bf(f1.w * 0.125f);
      qf[ch] = t;
    }
  }
  const int skey_l = l & 15;
  const int sd0 = wv * 16 + ((l >> 4) & 3) * 4;
  const int kk = l31;
  const int m2x = (kk >> 2) ^ ((kk & 3) << 1);
  const int kread = ((kk & 3) << 10) + (HL << 9) + (m2x << 4);
  const int vread = ((l & 3) << 8) + (HL << 7) + ((l31 >> 2) << 4);
  char* kb = (char*)klds;
  char* vb = (char*)vlds;
  f32x16 o0, o1;
#pragma unroll
  for (int r = 0; r < 16; ++r) { o0[r] = 0.f; o1[r] = 0.f; }
  float m_run = -1e30f, l_run = 0.f;
  for (int it = 0; it < NTILE; ++it) {
    const int kv0 = it * KVBLK;
    __syncthreads();
#pragma unroll
    for (int p = 0; p < 4; ++p) {
      const int key = skey_l + 16 * p;
      const float4 kf = *(const float4*)(K + base + (size_t)(kv0 + key) * DHEAD + sd0);
      const float4 vf = *(const float4*)(V + base + (size_t)(kv0 + key) * DHEAD + sd0);
      const int kkw = key & 31;
      const int m2w = (kkw >> 2) ^ ((kkw & 3) << 1);
      const int koff = ((key >> 5) << 12) + ((kkw & 3) << 10) + (((sd0 >> 3) & 1) << 9)
                     + ((sd0 >> 4) << 7) + (m2w << 4) + ((sd0 & 7) << 1);
      short4v kb4;
      kb4[0] = (short)f2bf(kf.x); kb4[1] = (short)f2bf(kf.y);
      kb4[2] = (short)f2bf(kf.z); kb4[3] = (short)f2bf(kf.w);
      *(short4v*)(kb + koff) = kb4;
      const int vbase2 = ((p * 2 + (sd0 >> 5)) << 10) + (((key >> 3) & 1) << 7)
                       + (((sd0 & 31) >> 2) << 4) + ((key & 7) << 1);
      *(short*)(vb + vbase2 + 0)   = (short)f2bf(vf.x);
      *(short*)(vb + vbase2 + 256) = (short)f2bf(vf.y);
      *(short*)(vb + vbase2 + 512) = (short)f2bf(vf.z);
      *(short*)(vb + vbase2 + 768) = (short)f2bf(vf.w);
    }
    __syncthreads();
    f32x16 s0, s1;
#pragma unroll
    for (int r = 0; r < 16; ++r) { s0[r] = 0.f; s1[r] = 0.f; }
#pragma unroll
    for (int ch = 0; ch < 4; ++ch) {
      const bf16x8 ka0 = *(const bf16x8*)(kb + kread + ch * 128);
      const bf16x8 ka1 = *(const bf16x8*)(kb + kread + ch * 128 + 4096);
      s0 = __builtin_amdgcn_mfma_f32_32x32x16_bf16(ka0, qf[ch], s0, 0, 0, 0);
      s1 = __builtin_amdgcn_mfma_f32_32x32x16_bf16(ka1, qf[ch], s1, 0, 0, 0);
    }
    float mx = s0[0];
#pragma unroll
    for (int r = 1; r < 16; ++r) mx = fmaxf(mx, s0[r]);
#pragma unroll
    for (int r = 0; r < 16; ++r) mx = fmaxf(mx, s1[r]);
    mx = fmaxf(mx, __shfl_xor(mx, 32));
    const float m_new = fmaxf(m_run, mx);
    const float alpha = __expf(m_run - m_new);
    m_run = m_new;
    float rsum = 0.f;
#pragma unroll
    for (int r = 0; r < 16; ++r) { s0[r] = __expf(s0[r] - m_new); rsum += s0[r]; }
#pragma unroll
    for (int r = 0; r < 16; ++r) { s1[r] = __expf(s1[r] - m_new); rsum += s1[r]; }
    rsum += __shfl_xor(rsum, 32);
    l_run = l_run * alpha + rsum;
    o0 *= alpha;
    o1 *= alpha;
    unsigned wreg[2][8], xreg[2][8];
#pragma unroll
    for (int g = 0; g < 8; ++g) {
      wreg[0][g] = pack2(s0[2 * g], s0[2 * g + 1]);
      wreg[1][g] = pack2(s1[2 * g], s1[2 * g + 1]);
    }
#pragma unroll
    for (int sub = 0; sub < 2; ++sub)
#pragma unroll
      for (int g = 0; g < 8; ++g)
        xreg[sub][g] = (unsigned)__shfl_xor((int)wreg[sub][g], 32);
#pragma unroll
    for (int ch = 0; ch < 4; ++ch) {
      const int sub = ch >> 1, e = ch & 1;
      const unsigned lo0 = hib ? xreg[sub][4 * e + 2] : wreg[sub][4 * e + 0];
      const unsigned lo1 = hib ? xreg[sub][4 * e + 3] : wreg[sub][4 * e + 1];
      const unsigned hi0 = hib ? wreg[sub][4 * e + 2] : xreg[sub][4 * e + 0];
      const unsigned hi1 = hib ? wreg[sub][4 * e + 3] : xreg[sub][4 * e + 1];
      BF8U pb;
      pb.u[0] = lo0; pb.u[1] = lo1; pb.u[2] = hi0; pb.u[3] = hi1;
      const bf16x8 va0 = *(const bf16x8*)(vb + vread + (ch * 2 + 0) * 1024);
      const bf16x8 va1 = *(const bf16x8*)(vb + vread + (ch * 2 + 1) * 1024);
      o0 = __builtin_amdgcn_mfma_f32_32x32x16_bf16(va0, pb.v, o0, 0, 0, 0);
      o1 = __builtin_amdgcn_mfma_f32_32x32x16_bf16(va1, pb.v, o1, 0, 0, 0);
    }
  }
  const float inv = 1.f / l_run;
  float* orow = O + base + (size_t)(q0 + l31) * DHEAD;
#pragma unroll
  for (int a = 0; a < 4; ++a) {
    float4 v0, v1;
    v0.x = o0[4 * a + 0] * inv; v0.y = o0[4 * a + 1] * inv;
    v0.z = o0[4 * a + 2] * inv; v0.w = o0[4 * a + 3] * inv;
    *(float4*)(orow + 8 * a + 4 * HL) = v0;
    v1.x = o1[4 * a + 0] * inv; v1.y = o1[4 * a + 1] * inv;
    v1.z = o1[4 * a + 2] * inv; v1.w = o1[4 * a + 3] * inv;
    *(float4*)(orow + 8 * a + 4 * HL + 32) = v1;
  }
}

extern "C" void kernel_launch(void* const* d_in, const int* in_sizes, int n_in,
                              void* d_out, int out_size, void* d_ws, size_t ws_size,
                              hipStream_t stream) {
  const float* q = (const float*)d_in[0];
  const float* k = (const float*)d_in[1];
  const float* v = (const float*)d_in[2];
  float* o = (float*)d_out;
  if (ws_size < WS_NEED) {
    dim3 grid(NSEQ / QBLK, NHTOT, 1);
    fattn_fb<<<grid, dim3(256, 1, 1), 0, stream>>>(q, k, v, o);
    return;
  }
  short* Qb = (short*)d_ws;
  char* KVb = (char*)d_ws + QB_BYTES;
  prep_kernel<<<dim3(4096 + NHTOT * NTILE, 1, 1), dim3(256, 1, 1), 0, stream>>>(q, k, v, Qb, KVb);
  dim3 grid(NHTOT, NSEQ / QBLK, 1);
  fattn_kernel<<<grid, dim3(256, 1, 1), 0, stream>>>(Qb, KVb, o);
}